// Round 1
// baseline (400.101 us; speedup 1.0000x reference)
//
#include <hip/hip_runtime.h>

#define PDIM 1024

// ---------------------------------------------------------------------------
// Kernel 1: hi[i] = hidden[i,:]·Wi ; hj[j] = hidden[j,:]·Wj  → hij[0:1024]=hi,
// hij[1024:2048]=hj.  Tiny (2048 dots of 64).
// ---------------------------------------------------------------------------
__global__ __launch_bounds__(256) void precompute_hij(
    const float* __restrict__ hidden, const float* __restrict__ W,
    float* __restrict__ hij)
{
    int idx = blockIdx.x * 256 + threadIdx.x;          // 0..2047
    int row = idx & (PDIM - 1);
    const float* w = W + 64 + ((idx >> 10) << 6);      // Wi at W+64, Wj at W+128
    const float4* h4 = reinterpret_cast<const float4*>(hidden + (row << 6));
    const float4* w4 = reinterpret_cast<const float4*>(w);
    float acc = 0.f;
#pragma unroll
    for (int k = 0; k < 16; ++k) {
        float4 a = h4[k], b = w4[k];
        acc += a.x * b.x + a.y * b.y + a.z * b.z + a.w * b.w;
    }
    hij[idx] = acc;
}

// ---------------------------------------------------------------------------
// Kernel 2: one block per row i.  256 threads = 4 waves.
//   phase A: scores + masked-pos into LDS (streams rela[i,:,:], 256 KB, coalesced)
//   phase B: block softmax (exact reference semantics)
//   phase C: out[i,:] = attn · hidden  (hidden served from L2)
// ---------------------------------------------------------------------------
__global__ __launch_bounds__(256) void social_row(
    const float* __restrict__ hidden,
    const float* __restrict__ rela,
    const int*   __restrict__ nei,
    const float* __restrict__ W,
    const float* __restrict__ bptr,
    const float* __restrict__ hij,
    float* __restrict__ out)
{
    __shared__ float s_pos[PDIM];   // scores → masked pos → attn (in place)
    __shared__ int   s_nei[PDIM];
    __shared__ float s_part[256];   // cross-wave matvec partials
    __shared__ float s_red[8];      // cross-wave softmax reduce

    const int i    = blockIdx.x;
    const int tid  = threadIdx.x;
    const int lane = tid & 63;
    const int wave = tid >> 6;      // 0..3
    const int q    = lane & 15;     // float4 chunk of the 64-dim
    const int sub  = lane >> 4;     // which j within the wave's quad

    // stage nei row into LDS (one coalesced int4 pass)
    {
        const int4* nr = reinterpret_cast<const int4*>(nei + ((size_t)i << 10));
        reinterpret_cast<int4*>(s_nei)[tid] = nr[tid];
    }

    const float hib = hij[i] + bptr[0];
    const float* hj = hij + PDIM;
    const float4 wr = reinterpret_cast<const float4*>(W)[q];   // Wr chunk

    __syncthreads();

    // ---- phase A: scores --------------------------------------------------
    // wave w handles j = w*4 + sub + 16*t, t = 0..63.  Wave reads 1 KB/iter.
    {
        const int jofs = (wave << 2) + sub;
        const float* rp = rela + (((size_t)i << 10) + jofs) * 64 + (q << 2);
#pragma unroll 4
        for (int t = 0; t < 64; ++t) {
            float4 rv = *reinterpret_cast<const float4*>(rp + (size_t)t * (16 * 64));
            float part = rv.x * wr.x + rv.y * wr.y + rv.z * wr.z + rv.w * wr.w;
            part += __shfl_xor(part, 1);
            part += __shfl_xor(part, 2);
            part += __shfl_xor(part, 4);
            part += __shfl_xor(part, 8);
            if (q == 0) {
                int j = jofs + (t << 4);
                float score = part + hib + hj[j];
                float pos = (s_nei[j] > 0) ? score : 0.0f;
                if (pos == 0.0f) pos = -1e-6f;
                s_pos[j] = pos;
            }
        }
    }
    __syncthreads();

    // ---- phase B: softmax over all 1024 pos values ------------------------
    float p0 = s_pos[tid];
    float p1 = s_pos[tid + 256];
    float p2 = s_pos[tid + 512];
    float p3 = s_pos[tid + 768];

    float m = fmaxf(fmaxf(p0, p1), fmaxf(p2, p3));
#pragma unroll
    for (int d = 1; d < 64; d <<= 1) m = fmaxf(m, __shfl_xor(m, d));
    if (lane == 0) s_red[wave] = m;
    __syncthreads();
    const float M = fmaxf(fmaxf(s_red[0], s_red[1]), fmaxf(s_red[2], s_red[3]));

    float e0 = __expf(p0 - M);
    float e1 = __expf(p1 - M);
    float e2 = __expf(p2 - M);
    float e3 = __expf(p3 - M);
    float s = e0 + e1 + e2 + e3;
#pragma unroll
    for (int d = 1; d < 64; d <<= 1) s += __shfl_xor(s, d);
    if (lane == 0) s_red[4 + wave] = s;
    __syncthreads();
    const float S = s_red[4] + s_red[5] + s_red[6] + s_red[7];
    const float inv = 1.0f / S;

    // attn (masked) back into s_pos — each thread owns its 4 slots
    s_pos[tid]       = (s_nei[tid]       > 0) ? e0 * inv : 0.0f;
    s_pos[tid + 256] = (s_nei[tid + 256] > 0) ? e1 * inv : 0.0f;
    s_pos[tid + 512] = (s_nei[tid + 512] > 0) ? e2 * inv : 0.0f;
    s_pos[tid + 768] = (s_nei[tid + 768] > 0) ? e3 * inv : 0.0f;
    __syncthreads();

    // ---- phase C: out[i,:] = attn · hidden --------------------------------
    {
        const float4* h4 = reinterpret_cast<const float4*>(hidden);
        const int jofs = (wave << 2) + sub;
        float4 acc = make_float4(0.f, 0.f, 0.f, 0.f);
#pragma unroll 4
        for (int t = 0; t < 64; ++t) {
            int j = jofs + (t << 4);
            float a = s_pos[j];
            float4 hv = h4[(j << 4) + q];
            acc.x += a * hv.x; acc.y += a * hv.y;
            acc.z += a * hv.z; acc.w += a * hv.w;
        }
        // reduce over sub (lanes xor 16, 32)
        acc.x += __shfl_xor(acc.x, 16); acc.x += __shfl_xor(acc.x, 32);
        acc.y += __shfl_xor(acc.y, 16); acc.y += __shfl_xor(acc.y, 32);
        acc.z += __shfl_xor(acc.z, 16); acc.z += __shfl_xor(acc.z, 32);
        acc.w += __shfl_xor(acc.w, 16); acc.w += __shfl_xor(acc.w, 32);
        if (sub == 0)
            reinterpret_cast<float4*>(s_part)[(wave << 4) + q] = acc;
    }
    __syncthreads();
    if (tid < 64) {
        float r = s_part[tid] + s_part[64 + tid] + s_part[128 + tid] + s_part[192 + tid];
        out[((size_t)i << 6) + tid] = r;
    }
}

// ---------------------------------------------------------------------------
extern "C" void kernel_launch(void* const* d_in, const int* in_sizes, int n_in,
                              void* d_out, int out_size, void* d_ws, size_t ws_size,
                              hipStream_t stream)
{
    const float* hidden = (const float*)d_in[0];   // (1024, 64) f32
    const float* rela   = (const float*)d_in[1];   // (1024, 1024, 64) f32
    // d_in[2] = corr_index — unused by the reference
    const int*   nei    = (const int*)d_in[3];     // (1024, 1024) i32
    const float* W      = (const float*)d_in[4];   // (192,) f32
    const float* bptr   = (const float*)d_in[5];   // scalar f32

    float* hij = (float*)d_ws;                     // 2048 floats

    precompute_hij<<<8, 256, 0, stream>>>(hidden, W, hij);
    social_row<<<PDIM, 256, 0, stream>>>(hidden, rela, nei, W, bptr, hij,
                                         (float*)d_out);
}

// Round 2
// 353.457 us; speedup vs baseline: 1.1320x; 1.1320x over previous
//
#include <hip/hip_runtime.h>

#define PDIM 1024

// ---------------------------------------------------------------------------
// Kernel 1: hi[i] = hidden[i,:]·Wi ; hj[j] = hidden[j,:]·Wj  → hij[0:1024]=hi,
// hij[1024:2048]=hj.
// ---------------------------------------------------------------------------
__global__ __launch_bounds__(256) void precompute_hij(
    const float* __restrict__ hidden, const float* __restrict__ W,
    float* __restrict__ hij)
{
    int idx = blockIdx.x * 256 + threadIdx.x;          // 0..2047
    int row = idx & (PDIM - 1);
    const float* w = W + 64 + ((idx >> 10) << 6);      // Wi at W+64, Wj at W+128
    const float4* h4 = reinterpret_cast<const float4*>(hidden + (row << 6));
    const float4* w4 = reinterpret_cast<const float4*>(w);
    float acc = 0.f;
#pragma unroll
    for (int k = 0; k < 16; ++k) {
        float4 a = h4[k], b = w4[k];
        acc += a.x * b.x + a.y * b.y + a.z * b.z + a.w * b.w;
    }
    hij[idx] = acc;
}

// ---------------------------------------------------------------------------
// Kernel 2: one block per row i, 256 threads = 4 waves.
//   phase A: thread t owns j = 4t..4t+3; computes rela·Wr ONLY where nei>0
//            (masked rows issue no global loads — halves HBM traffic)
//   phase B: exact masked softmax semantics of the reference
//   phase C: out[i,:] = attn · hidden  (hidden is L2-resident)
// ---------------------------------------------------------------------------
__global__ __launch_bounds__(256) void social_row(
    const float* __restrict__ hidden,
    const float* __restrict__ rela,
    const int*   __restrict__ nei,
    const float* __restrict__ W,
    const float* __restrict__ bptr,
    const float* __restrict__ hij,
    float* __restrict__ out)
{
    __shared__ float s_pos[PDIM];   // attn weights for phase C
    __shared__ float s_part[256];   // cross-wave matvec partials
    __shared__ float s_red[8];      // cross-wave softmax reduce

    const int i    = blockIdx.x;
    const int tid  = threadIdx.x;
    const int lane = tid & 63;
    const int wave = tid >> 6;      // 0..3

    // nei values for the 4 rows this thread owns (j = 4*tid + k)
    const int4 nv = reinterpret_cast<const int4*>(nei + ((size_t)i << 10))[tid];
    const int act[4] = { nv.x > 0, nv.y > 0, nv.z > 0, nv.w > 0 };

    const float hib = hij[i] + bptr[0];
    const float* hj = hij + PDIM;

    // ---- phase A: masked scores ------------------------------------------
    float pos[4];
#pragma unroll
    for (int k = 0; k < 4; ++k) {
        const int j = (tid << 2) + k;
        float p = -1e-6f;                      // masked value
        if (act[k]) {
            const float4* rp = reinterpret_cast<const float4*>(
                rela + ((((size_t)i << 10) + j) << 6));
            float a0 = 0.f, a1 = 0.f, a2 = 0.f, a3 = 0.f;
#pragma unroll
            for (int c = 0; c < 16; c += 4) {
                float4 r0 = rp[c], r1 = rp[c + 1], r2 = rp[c + 2], r3 = rp[c + 3];
                // W[] indices are uniform → scalar-register operands
                a0 += r0.x * W[4*c+0]  + r0.y * W[4*c+1]  + r0.z * W[4*c+2]  + r0.w * W[4*c+3];
                a1 += r1.x * W[4*c+4]  + r1.y * W[4*c+5]  + r1.z * W[4*c+6]  + r1.w * W[4*c+7];
                a2 += r2.x * W[4*c+8]  + r2.y * W[4*c+9]  + r2.z * W[4*c+10] + r2.w * W[4*c+11];
                a3 += r3.x * W[4*c+12] + r3.y * W[4*c+13] + r3.z * W[4*c+14] + r3.w * W[4*c+15];
            }
            float score = (a0 + a1) + (a2 + a3) + hib + hj[j];
            p = (score == 0.0f) ? -1e-6f : score;   // reference's Pos==0 pin
        }
        pos[k] = p;
    }

    // ---- phase B: softmax over all 1024 pos values ------------------------
    float m = fmaxf(fmaxf(pos[0], pos[1]), fmaxf(pos[2], pos[3]));
#pragma unroll
    for (int d = 1; d < 64; d <<= 1) m = fmaxf(m, __shfl_xor(m, d));
    if (lane == 0) s_red[wave] = m;
    __syncthreads();
    const float M = fmaxf(fmaxf(s_red[0], s_red[1]), fmaxf(s_red[2], s_red[3]));

    float e0 = __expf(pos[0] - M);
    float e1 = __expf(pos[1] - M);
    float e2 = __expf(pos[2] - M);
    float e3 = __expf(pos[3] - M);
    float s = (e0 + e1) + (e2 + e3);
#pragma unroll
    for (int d = 1; d < 64; d <<= 1) s += __shfl_xor(s, d);
    if (lane == 0) s_red[4 + wave] = s;
    __syncthreads();
    const float S = s_red[4] + s_red[5] + s_red[6] + s_red[7];
    const float inv = 1.0f / S;

    // attn (masked) into LDS — thread owns j = 4*tid..4*tid+3 (float4 write)
    float4 attn;
    attn.x = act[0] ? e0 * inv : 0.0f;
    attn.y = act[1] ? e1 * inv : 0.0f;
    attn.z = act[2] ? e2 * inv : 0.0f;
    attn.w = act[3] ? e3 * inv : 0.0f;
    reinterpret_cast<float4*>(s_pos)[tid] = attn;
    __syncthreads();

    // ---- phase C: out[i,:] = attn · hidden --------------------------------
    {
        const int q   = lane & 15;      // float4 chunk of the 64-dim
        const int sub = lane >> 4;      // j within the wave's quad
        const float4* h4 = reinterpret_cast<const float4*>(hidden);
        const int jofs = (wave << 2) + sub;
        float4 acc = make_float4(0.f, 0.f, 0.f, 0.f);
#pragma unroll 4
        for (int t = 0; t < 64; ++t) {
            int j = jofs + (t << 4);
            float a = s_pos[j];
            float4 hv = h4[(j << 4) + q];
            acc.x += a * hv.x; acc.y += a * hv.y;
            acc.z += a * hv.z; acc.w += a * hv.w;
        }
        acc.x += __shfl_xor(acc.x, 16); acc.x += __shfl_xor(acc.x, 32);
        acc.y += __shfl_xor(acc.y, 16); acc.y += __shfl_xor(acc.y, 32);
        acc.z += __shfl_xor(acc.z, 16); acc.z += __shfl_xor(acc.z, 32);
        acc.w += __shfl_xor(acc.w, 16); acc.w += __shfl_xor(acc.w, 32);
        if (sub == 0)
            reinterpret_cast<float4*>(s_part)[(wave << 4) + q] = acc;
    }
    __syncthreads();
    if (tid < 64) {
        float r = s_part[tid] + s_part[64 + tid] + s_part[128 + tid] + s_part[192 + tid];
        out[((size_t)i << 6) + tid] = r;
    }
}

// ---------------------------------------------------------------------------
extern "C" void kernel_launch(void* const* d_in, const int* in_sizes, int n_in,
                              void* d_out, int out_size, void* d_ws, size_t ws_size,
                              hipStream_t stream)
{
    const float* hidden = (const float*)d_in[0];   // (1024, 64) f32
    const float* rela   = (const float*)d_in[1];   // (1024, 1024, 64) f32
    // d_in[2] = corr_index — unused by the reference
    const int*   nei    = (const int*)d_in[3];     // (1024, 1024) i32
    const float* W      = (const float*)d_in[4];   // (192,) f32
    const float* bptr   = (const float*)d_in[5];   // scalar f32

    float* hij = (float*)d_ws;                     // 2048 floats

    precompute_hij<<<8, 256, 0, stream>>>(hidden, W, hij);
    social_row<<<PDIM, 256, 0, stream>>>(hidden, rela, nei, W, bptr, hij,
                                         (float*)d_out);
}

// Round 3
// 348.603 us; speedup vs baseline: 1.1477x; 1.0139x over previous
//
#include <hip/hip_runtime.h>

#define PDIM 1024

// One block per row i. 256 threads = 4 waves = 16 teams of 16 lanes.
//  setup : stage nei (int4/thread), ballot-compact active j list, team-0
//          computes hib = hidden[i]·Wi + b
//  phase A: team per active row j — coalesced 256B rela row + L2-hit hidden
//           row, fused dot (rela·Wr + hidden[j]·Wj), 4-step shfl reduce
//  phase B: exact reference masked-softmax semantics
//  phase C: team per active row j — acc += attn[j] * hidden[j], cross-team
//           LDS reduce
__global__ __launch_bounds__(256) void social_row(
    const float* __restrict__ hidden,
    const float* __restrict__ rela,
    const int*   __restrict__ nei,
    const float* __restrict__ W,
    const float* __restrict__ bptr,
    float* __restrict__ out)
{
    __shared__ float s_pos[PDIM];    // scores → attn (in place)
    __shared__ int   s_list[PDIM];   // compacted active j
    __shared__ float s_part[PDIM];   // 16 teams × 64 dims
    __shared__ float s_red[8];
    __shared__ int   s_wsum[4];
    __shared__ float s_hib;

    const int i    = blockIdx.x;
    const int tid  = threadIdx.x;
    const int lane = tid & 63;
    const int wave = tid >> 6;      // 0..3
    const int q    = tid & 15;      // float4 chunk of the 64-dim
    const int tm   = tid >> 4;      // team 0..15 (block-wide)

    // ---- stage nei + init scores to the masked value ----------------------
    const int4 nv = reinterpret_cast<const int4*>(nei + ((size_t)i << 10))[tid];
    const int a0 = nv.x > 0, a1 = nv.y > 0, a2 = nv.z > 0, a3 = nv.w > 0;
    reinterpret_cast<float4*>(s_pos)[tid] =
        make_float4(-1e-6f, -1e-6f, -1e-6f, -1e-6f);

    // per-lane W chunks: Wr = W[0:64], Wi = W[64:128], Wj = W[128:192]
    const float4 wr = reinterpret_cast<const float4*>(W)[q];
    const float4 wj = reinterpret_cast<const float4*>(W)[32 + q];

    // ---- hib = hidden[i]·Wi + b  (team 0, wave 0) -------------------------
    if (tid < 16) {
        float4 hv = reinterpret_cast<const float4*>(hidden)[(i << 4) + tid];
        float4 wi = reinterpret_cast<const float4*>(W)[16 + tid];
        float p = hv.x * wi.x + hv.y * wi.y + hv.z * wi.z + hv.w * wi.w;
        p += __shfl_xor(p, 1); p += __shfl_xor(p, 2);
        p += __shfl_xor(p, 4); p += __shfl_xor(p, 8);
        if (tid == 0) s_hib = p + bptr[0];
    }

    // ---- compact the active-j list via ballot prefix ----------------------
    const unsigned long long b0 = __ballot(a0);
    const unsigned long long b1 = __ballot(a1);
    const unsigned long long b2 = __ballot(b2 != b2 ? a2 : a2); // a2
    const unsigned long long b3 = __ballot(a3);
    const int t0 = __popcll(b0), t1 = __popcll(b1),
              t2 = __popcll(b2), t3 = __popcll(b3);
    if (lane == 0) s_wsum[wave] = t0 + t1 + t2 + t3;
    __syncthreads();

    int woff = 0;
#pragma unroll
    for (int u = 0; u < 4; ++u) woff += (u < wave) ? s_wsum[u] : 0;
    const int nAct = s_wsum[0] + s_wsum[1] + s_wsum[2] + s_wsum[3];
    const unsigned long long lt = (1ull << lane) - 1ull;   // lanes below me
    const int jb = tid << 2;
    if (a0) s_list[woff + __popcll(b0 & lt)] = jb;
    if (a1) s_list[woff + t0 + __popcll(b1 & lt)] = jb + 1;
    if (a2) s_list[woff + t0 + t1 + __popcll(b2 & lt)] = jb + 2;
    if (a3) s_list[woff + t0 + t1 + t2 + __popcll(b3 & lt)] = jb + 3;
    __syncthreads();

    const float hib = s_hib;
    const float4* h4 = reinterpret_cast<const float4*>(hidden);

    // ---- phase A: fused scores over active rows only ----------------------
#pragma unroll 2
    for (int e = tm; e < nAct; e += 16) {
        const int j = s_list[e];
        const float4 rv = reinterpret_cast<const float4*>(
            rela + ((((size_t)i << 10) + j) << 6))[q];
        const float4 hv = h4[(j << 4) + q];
        float p = rv.x * wr.x + rv.y * wr.y + rv.z * wr.z + rv.w * wr.w
                + hv.x * wj.x + hv.y * wj.y + hv.z * wj.z + hv.w * wj.w;
        p += __shfl_xor(p, 1); p += __shfl_xor(p, 2);
        p += __shfl_xor(p, 4); p += __shfl_xor(p, 8);
        if (q == 0) {
            float score = p + hib;
            s_pos[j] = (score == 0.0f) ? -1e-6f : score;  // Pos==0 pin
        }
    }
    __syncthreads();

    // ---- phase B: softmax over all 1024 pos values ------------------------
    const float4 p4 = reinterpret_cast<const float4*>(s_pos)[tid];
    float m = fmaxf(fmaxf(p4.x, p4.y), fmaxf(p4.z, p4.w));
#pragma unroll
    for (int d = 1; d < 64; d <<= 1) m = fmaxf(m, __shfl_xor(m, d));
    if (lane == 0) s_red[wave] = m;
    __syncthreads();
    const float M = fmaxf(fmaxf(s_red[0], s_red[1]), fmaxf(s_red[2], s_red[3]));

    const float e0 = __expf(p4.x - M);
    const float e1 = __expf(p4.y - M);
    const float e2 = __expf(p4.z - M);
    const float e3 = __expf(p4.w - M);
    float s = (e0 + e1) + (e2 + e3);
#pragma unroll
    for (int d = 1; d < 64; d <<= 1) s += __shfl_xor(s, d);
    if (lane == 0) s_red[4 + wave] = s;
    __syncthreads();
    const float S = s_red[4] + s_red[5] + s_red[6] + s_red[7];
    const float inv = 1.0f / S;

    float4 attn;
    attn.x = a0 ? e0 * inv : 0.0f;
    attn.y = a1 ? e1 * inv : 0.0f;
    attn.z = a2 ? e2 * inv : 0.0f;
    attn.w = a3 ? e3 * inv : 0.0f;
    reinterpret_cast<float4*>(s_pos)[tid] = attn;
    __syncthreads();

    // ---- phase C: out[i,:] = attn · hidden over active rows only ----------
    float4 acc = make_float4(0.f, 0.f, 0.f, 0.f);
#pragma unroll 2
    for (int e = tm; e < nAct; e += 16) {
        const int j = s_list[e];
        const float a = s_pos[j];
        const float4 hv = h4[(j << 4) + q];
        acc.x += a * hv.x; acc.y += a * hv.y;
        acc.z += a * hv.z; acc.w += a * hv.w;
    }
    reinterpret_cast<float4*>(s_part)[(tm << 4) + q] = acc;
    __syncthreads();

    if (tid < 64) {
        float r = 0.f;
#pragma unroll
        for (int t = 0; t < 16; ++t) r += s_part[(t << 6) + tid];
        out[((size_t)i << 6) + tid] = r;
    }
}

// ---------------------------------------------------------------------------
extern "C" void kernel_launch(void* const* d_in, const int* in_sizes, int n_in,
                              void* d_out, int out_size, void* d_ws, size_t ws_size,
                              hipStream_t stream)
{
    const float* hidden = (const float*)d_in[0];   // (1024, 64) f32
    const float* rela   = (const float*)d_in[1];   // (1024, 1024, 64) f32
    // d_in[2] = corr_index — unused by the reference
    const int*   nei    = (const int*)d_in[3];     // (1024, 1024) i32
    const float* W      = (const float*)d_in[4];   // (192,) f32
    const float* bptr   = (const float*)d_in[5];   // scalar f32

    social_row<<<PDIM, 256, 0, stream>>>(hidden, rela, nei, W, bptr,
                                         (float*)d_out);
}